// Round 11
// baseline (15406.454 us; speedup 1.0000x reference)
//
#include <hip/hip_runtime.h>
#include <hip/hip_bf16.h>

// LSTM: L=1024, B=64, I=512, H=512, fp32 in/out.
// Persistent kernel, 256 WGs x 256 thr (1 WG/CU). 8 clusters x 32 WGs;
// cluster = 8 batches; wave = 16 gate rows (4 h-idx x 4 gates). Weights in
// VGPRs; C state in registers. Exchange protocol = round 8 (proven 5824us):
// parity-coded h stores (no drain), advisory per-wave flags, mandatory
// flag-wait then parity-validated h-load.
// ROUND-11: X-GEMM HOISTED OUT OF THE RECURRENT LOOP. Wave (cl,wg,wv)
// consumes exactly the x-gate partials it alone produces, so a prologue
// computes gx[t] = x_t @ Wx^T + b for all t into a PRIVATE d_ws slice
// (no sync, no exchange), and the recurrent loop streams it back with a
// one-step prefetch. Recurrent critical path loses all x loads + pack8 +
// 16 of 32 MFMAs. Host gates on ws_size (deterministic): fp32 gx (512MB),
// bf16 gx (256MB), or verbatim round-8 fallback.
// hx memset 0x7F each launch: u16 0x7F7F has bit14=1 -> fails parity-0;
// erases ALL cross-replay data (the round-8 stale-parity hole).

typedef __attribute__((ext_vector_type(8))) short bf16x8;
typedef __attribute__((ext_vector_type(4))) float f32x4;
typedef __attribute__((ext_vector_type(2))) unsigned int u32x2;

#define NT 1024
#define NB 64
#define NH 512
#define NI 512

#define FLAG_BYTES 4096
#define HX_BYTES   (2 * NB * NH * 2)            // 128 KiB
#define SLICE32    ((size_t)NT * 32 * 16)       // 512 KiB / wave
#define SLICE16    ((size_t)NT * 32 * 8)        // 256 KiB / wave
#define GXB32      (1024ull * SLICE32)          // 512 MiB
#define GXB16      (1024ull * SLICE16)          // 256 MiB

#define VBITS 0x4000400040004000ULL             // bit14 of each u16 lane

__device__ __forceinline__ bf16x8 pack8(float4 a, float4 b) {
    union U2 { __hip_bfloat162 h; unsigned int u; } c0, c1, c2, c3;
    c0.h = __float22bfloat162_rn(make_float2(a.x, a.y));
    c1.h = __float22bfloat162_rn(make_float2(a.z, a.w));
    c2.h = __float22bfloat162_rn(make_float2(b.x, b.y));
    c3.h = __float22bfloat162_rn(make_float2(b.z, b.w));
    union R { bf16x8 v; unsigned int u[4]; } r;
    r.u[0] = c0.u; r.u[1] = c1.u; r.u[2] = c2.u; r.u[3] = c3.u;
    return r.v;
}

__device__ __forceinline__ float sigm(float v) {
    return 1.0f / (1.0f + __expf(-v));
}
__device__ __forceinline__ float tanh_f(float v) {
    float e = __expf(-2.0f * fabsf(v));        // in (0,1], no overflow
    float r = (1.0f - e) / (1.0f + e);         // <= 1 in fp32
    return copysignf(r, v);
}
__device__ __forceinline__ float bf16hi_f(unsigned int u) {   // bits[31:16]
    union { unsigned int u; float f; } c; c.u = u & 0xFFFF0000u; return c.f;
}
__device__ __forceinline__ float bf16lo_f(unsigned int u) {   // bits[15:0]
    union { unsigned int u; float f; } c; c.u = u << 16; return c.f;
}

// GXMODE: 0 = in-loop x (round-8 verbatim), 1 = fp32 gx, 2 = bf16 gx
template<int GXMODE>
__global__ __launch_bounds__(256, 1) void lstm_fused(
    const float* __restrict__ x,
    const float* __restrict__ h0,
    const float* __restrict__ c0,
    const float* __restrict__ Wf, const float* __restrict__ Bf,
    const float* __restrict__ Wi, const float* __restrict__ Bi,
    const float* __restrict__ Wc, const float* __restrict__ Bc,
    const float* __restrict__ Wo, const float* __restrict__ Bo,
    float* __restrict__ out,
    unsigned int* __restrict__ flags,
    unsigned short* __restrict__ hx,
    char* __restrict__ gxws)
{
    const int tid  = threadIdx.x;
    const int wv   = tid >> 6;            // wave 0..3
    const int lane = tid & 63;
    const int n    = lane & 15;           // D col (gate row within wave tile)
    const int kg   = lane >> 4;           // k-group 0..3
    const int cl   = blockIdx.x & 7;      // cluster (XCD-swizzle heuristic)
    const int wg   = blockIdx.x >> 3;     // WG within cluster, 0..31

    const int jj = (wv << 2) + (n >> 2);          // 0..15 within WG
    const int j  = (wg << 4) + jj;                // global h index
    const int g  = n & 3;                         // 0=f 1=i 2=c 3=o

    const float* Wg = (g == 0) ? Wf : (g == 1) ? Wi : (g == 2) ? Wc : Wo;
    const float* Bg = (g == 0) ? Bf : (g == 1) ? Bi : (g == 2) ? Bc : Bo;

    const int m_a   = (n < 8) ? n : 7;            // A-row batch (8..15 dup)
    const int bglob = cl * 8 + m_a;

    // ---- prologue: static B-fragments (weights, bf16) into VGPRs ----
    bf16x8 bfrag[32];                             // [0..15]=h-part, [16..31]=x
    {
        const float* wrow = Wg + (size_t)j * (NH + NI);
        #pragma unroll
        for (int kb = 0; kb < 32; ++kb) {
            const float* p = wrow + kb * 32 + kg * 8;
            bfrag[kb] = pack8(*(const float4*)(p), *(const float4*)(p + 4));
        }
    }
    const float bias_v = Bg[j];

    const bool active = (g == 0) && (kg < 2);     // 8 lanes/wave x 4 regs
    float Cst[4];
    #pragma unroll
    for (int r = 0; r < 4; ++r)
        Cst[r] = active ? c0[(size_t)(cl * 8 + kg * 4 + r) * NH + j] : 0.0f;

    unsigned int* fb = flags + cl * 128;          // 128 wave-flags, 512 B
    const int myflag = wg * 4 + wv;

    // ---- gx prologue: private x@Wx^T+b for all t (no sync needed) ----
    char* slice = nullptr;
    const int li = (kg << 4) + n;                 // 0..31 for kg<2
    if constexpr (GXMODE > 0) {
        const int wid = blockIdx.x * 4 + wv;      // 0..1023
        slice = gxws + (size_t)wid * (GXMODE == 1 ? SLICE32 : SLICE16);
        for (int t = 0; t < NT; ++t) {
            const float* xrow = x + ((size_t)t * NB + bglob) * NI;
            bf16x8 xfrag[16];
            #pragma unroll
            for (int q = 0; q < 16; ++q) {
                const float* p = xrow + q * 32 + kg * 8;
                xfrag[q] = pack8(*(const float4*)(p), *(const float4*)(p + 4));
            }
            f32x4 a0 = {bias_v, bias_v, bias_v, bias_v};
            f32x4 a1 = {0.f, 0.f, 0.f, 0.f};
            f32x4 a2 = {0.f, 0.f, 0.f, 0.f};
            f32x4 a3 = {0.f, 0.f, 0.f, 0.f};
            #pragma unroll
            for (int q = 0; q < 16; q += 4) {
                a0 = __builtin_amdgcn_mfma_f32_16x16x32_bf16(xfrag[q],     bfrag[16 + q],     a0, 0, 0, 0);
                a1 = __builtin_amdgcn_mfma_f32_16x16x32_bf16(xfrag[q + 1], bfrag[16 + q + 1], a1, 0, 0, 0);
                a2 = __builtin_amdgcn_mfma_f32_16x16x32_bf16(xfrag[q + 2], bfrag[16 + q + 2], a2, 0, 0, 0);
                a3 = __builtin_amdgcn_mfma_f32_16x16x32_bf16(xfrag[q + 3], bfrag[16 + q + 3], a3, 0, 0, 0);
            }
            f32x4 acc = (a0 + a1) + (a2 + a3);
            if (kg < 2) {
                if constexpr (GXMODE == 1) {
                    *(f32x4*)(slice + ((size_t)t * 32 + li) * 16) = acc;
                } else {
                    union { __hip_bfloat162 h; unsigned int u; } p0, p1;
                    p0.h = __float22bfloat162_rn(make_float2(acc[0], acc[1]));
                    p1.h = __float22bfloat162_rn(make_float2(acc[2], acc[3]));
                    u32x2 v = {p0.u, p1.u};
                    *(u32x2*)(slice + ((size_t)t * 32 + li) * 8) = v;
                }
            }
        }
        // pin same-wave store->load ordering before the recurrent reads
        asm volatile("s_waitcnt vmcnt(0)" ::: "memory");
    }

    // preload gx(0)
    f32x4 gxv = {0.f, 0.f, 0.f, 0.f};
    if constexpr (GXMODE == 1) {
        if (kg < 2) gxv = *(const f32x4*)(slice + (size_t)li * 16);
    } else if constexpr (GXMODE == 2) {
        if (kg < 2) {
            u32x2 v = *(const u32x2*)(slice + (size_t)li * 8);
            gxv[0] = bf16lo_f(v.x); gxv[1] = bf16hi_f(v.x);
            gxv[2] = bf16lo_f(v.y); gxv[3] = bf16hi_f(v.y);
        }
    }

    for (int t = 0; t < NT; ++t) {
        f32x4 a0, a1, a2, a3;
        if constexpr (GXMODE == 0) {
            // -- in-loop x fragments + x-partial MFMAs (round-8 verbatim) --
            const float* xrow = x + ((size_t)t * NB + bglob) * NI;
            bf16x8 xfrag[16];
            #pragma unroll
            for (int q = 0; q < 16; ++q) {
                const float* p = xrow + q * 32 + kg * 8;
                xfrag[q] = pack8(*(const float4*)(p), *(const float4*)(p + 4));
            }
            a0 = (f32x4){bias_v, bias_v, bias_v, bias_v};
            a1 = (f32x4){0.f, 0.f, 0.f, 0.f};
            a2 = (f32x4){0.f, 0.f, 0.f, 0.f};
            a3 = (f32x4){0.f, 0.f, 0.f, 0.f};
            #pragma unroll
            for (int q = 0; q < 16; q += 4) {
                a0 = __builtin_amdgcn_mfma_f32_16x16x32_bf16(xfrag[q],     bfrag[16 + q],     a0, 0, 0, 0);
                a1 = __builtin_amdgcn_mfma_f32_16x16x32_bf16(xfrag[q + 1], bfrag[16 + q + 1], a1, 0, 0, 0);
                a2 = __builtin_amdgcn_mfma_f32_16x16x32_bf16(xfrag[q + 2], bfrag[16 + q + 2], a2, 0, 0, 0);
                a3 = __builtin_amdgcn_mfma_f32_16x16x32_bf16(xfrag[q + 3], bfrag[16 + q + 3], a3, 0, 0, 0);
            }
        } else {
            a0 = gxv;                              // bias + x-part, prefetched
            a1 = (f32x4){0.f, 0.f, 0.f, 0.f};
            a2 = (f32x4){0.f, 0.f, 0.f, 0.f};
            a3 = (f32x4){0.f, 0.f, 0.f, 0.f};
        }

        // -- wait: all 128 producer waves of step t-1 (one u64 load/lane) --
        if (t > 0) {
            const unsigned int tgt = (unsigned int)t;
            const unsigned long long* fp =
                (const unsigned long long*)fb + lane;
            int guard = 1 << 20;
            for (;;) {
                unsigned long long fv = __hip_atomic_load(
                    fp, __ATOMIC_RELAXED, __HIP_MEMORY_SCOPE_AGENT);
                bool ok = ((unsigned int)fv >= tgt) &&
                          ((unsigned int)(fv >> 32) >= tgt);
                if (__all(ok)) break;
                if (--guard == 0) break;          // hang safety
                __builtin_amdgcn_s_sleep(1);
            }
            __builtin_amdgcn_sched_barrier(0);    // keep h-loads after spin
        }

        // -- h fragments: load + parity-validate (authoritative check) --
        bf16x8 hfrag[16];
        if (t == 0) {
            const float* hrow = h0 + (size_t)bglob * NH;
            #pragma unroll
            for (int q = 0; q < 16; ++q) {
                const float* p = hrow + q * 32 + kg * 8;
                hfrag[q] = pack8(*(const float4*)(p), *(const float4*)(p + 4));
            }
        } else {
            const unsigned long long pm64 =
                (((t - 1) >> 1) & 1) ? ~0ULL : 0ULL;
            const unsigned short* hrow =
                hx + ((size_t)((t - 1) & 1) * NB + bglob) * NH;
            int guard = 1 << 16;
            for (;;) {
                unsigned long long accb = 0;
                #pragma unroll
                for (int q = 0; q < 16; ++q) {
                    const unsigned long long* p =
                        (const unsigned long long*)(hrow + q * 32 + kg * 8);
                    union { bf16x8 v; unsigned long long u[2]; } un;
                    unsigned long long w0 = __hip_atomic_load(
                        p, __ATOMIC_RELAXED, __HIP_MEMORY_SCOPE_AGENT) ^ pm64;
                    unsigned long long w1 = __hip_atomic_load(
                        p + 1, __ATOMIC_RELAXED, __HIP_MEMORY_SCOPE_AGENT) ^ pm64;
                    accb |= w0;
                    accb |= w1;
                    un.u[0] = w0;
                    un.u[1] = w1;
                    hfrag[q] = un.v;
                }
                if (__all((accb & VBITS) == 0ULL)) break;  // all words fresh
                if (--guard == 0) break;          // hang safety
            }
            __builtin_amdgcn_sched_barrier(0);
        }

        #pragma unroll
        for (int q = 0; q < 16; q += 4) {
            a0 = __builtin_amdgcn_mfma_f32_16x16x32_bf16(hfrag[q],     bfrag[q],     a0, 0, 0, 0);
            a1 = __builtin_amdgcn_mfma_f32_16x16x32_bf16(hfrag[q + 1], bfrag[q + 1], a1, 0, 0, 0);
            a2 = __builtin_amdgcn_mfma_f32_16x16x32_bf16(hfrag[q + 2], bfrag[q + 2], a2, 0, 0, 0);
            a3 = __builtin_amdgcn_mfma_f32_16x16x32_bf16(hfrag[q + 3], bfrag[q + 3], a3, 0, 0, 0);
        }
        f32x4 acc = (a0 + a1) + (a2 + a3);

        // -- gather f/i/c/o in 4-lane groups, elementwise, coded h-store --
        unsigned short* hxout = hx + (size_t)(t & 1) * NB * NH;
        const unsigned int pmask = ((t >> 1) & 1) ? 0xFFFFu : 0u;
        float harr[4];
        #pragma unroll
        for (int r = 0; r < 4; ++r) {
            float fv = acc[r];
            float iv = __shfl_xor(fv, 1);
            float gv = __shfl_xor(fv, 2);
            float ov = __shfl_xor(fv, 3);
            if (active) {
                float ft = sigm(fv);
                float it = sigm(iv);
                float gt = tanh_f(gv);
                float ot = sigm(ov);
                float Cn = ft * Cst[r] + it * gt;
                Cst[r] = Cn;
                float ht = ot * tanh_f(Cn);       // |ht| <= 1.0 in fp32
                harr[r] = ht;
                int m = kg * 4 + r;               // batch within cluster
                __hip_bfloat16 hb = __float2bfloat16(ht);
                unsigned short code =
                    (unsigned short)((*(unsigned short*)&hb) ^ pmask);
                __hip_atomic_store(
                    (unsigned short*)(hxout + (size_t)(cl * 8 + m) * NH + j),
                    code, __ATOMIC_RELAXED, __HIP_MEMORY_SCOPE_AGENT);
            }
        }

        // -- advisory flag: NO drain (parity is the real gate) --
        __builtin_amdgcn_sched_barrier(0);        // keep flag after h-stores
        if (lane == 0)
            __hip_atomic_store(fb + myflag, (unsigned int)(t + 1),
                               __ATOMIC_RELAXED, __HIP_MEMORY_SCOPE_AGENT);

        // -- fp32 output stores AFTER publish (off the critical path) --
        if (active) {
            #pragma unroll
            for (int r = 0; r < 4; ++r) {
                int m = kg * 4 + r;
                out[((size_t)t * NB + cl * 8 + m) * NH + j] = harr[r];
            }
        }

        // -- prefetch gx(t+1): private, one full iteration to cover HBM --
        if constexpr (GXMODE == 1) {
            int tn = (t + 1 < NT) ? t + 1 : NT - 1;
            if (kg < 2)
                gxv = *(const f32x4*)(slice + ((size_t)tn * 32 + li) * 16);
        } else if constexpr (GXMODE == 2) {
            int tn = (t + 1 < NT) ? t + 1 : NT - 1;
            if (kg < 2) {
                u32x2 v = *(const u32x2*)(slice + ((size_t)tn * 32 + li) * 8);
                gxv[0] = bf16lo_f(v.x); gxv[1] = bf16hi_f(v.x);
                gxv[2] = bf16lo_f(v.y); gxv[3] = bf16hi_f(v.y);
            }
        }
    }
}

extern "C" void kernel_launch(void* const* d_in, const int* in_sizes, int n_in,
                              void* d_out, int out_size, void* d_ws, size_t ws_size,
                              hipStream_t stream) {
    const float* x  = (const float*)d_in[0];
    const float* h0 = (const float*)d_in[1];
    const float* c0 = (const float*)d_in[2];
    const float* Wf = (const float*)d_in[3];
    const float* Bf = (const float*)d_in[4];
    const float* Wi = (const float*)d_in[5];
    const float* Bi = (const float*)d_in[6];
    const float* Wc = (const float*)d_in[7];
    const float* Bc = (const float*)d_in[8];
    const float* Wo = (const float*)d_in[9];
    const float* Bo = (const float*)d_in[10];
    float* out = (float*)d_out;

    // Deterministic mode select on ws_size (constant across replays).
    int mode;
    size_t gxb;
    if      (ws_size >= GXB32 + FLAG_BYTES + HX_BYTES) { mode = 1; gxb = GXB32; }
    else if (ws_size >= GXB16 + FLAG_BYTES + HX_BYTES) { mode = 2; gxb = GXB16; }
    else                                               { mode = 0; gxb = 0;     }

    char*           ws    = (char*)d_ws;
    char*           gxws  = ws;                       // [gx][flags][hx]
    unsigned int*   flags = (unsigned int*)(ws + gxb);
    unsigned short* hx    = (unsigned short*)(ws + gxb + FLAG_BYTES);

    // Flags: zero each launch (monotonic, must restart).
    hipMemsetAsync(flags, 0, FLAG_BYTES, stream);
    // hx: 0x7F each launch -> u16 0x7F7F has bit14==1, fails the parity-0
    // validator; erases all cross-replay data (closes the stale-parity hole).
    hipMemsetAsync(hx, 0x7F, HX_BYTES, stream);

    if (mode == 1)
        lstm_fused<1><<<dim3(256), dim3(256), 0, stream>>>(
            x, h0, c0, Wf, Bf, Wi, Bi, Wc, Bc, Wo, Bo, out, flags, hx, gxws);
    else if (mode == 2)
        lstm_fused<2><<<dim3(256), dim3(256), 0, stream>>>(
            x, h0, c0, Wf, Bf, Wi, Bi, Wc, Bc, Wo, Bo, out, flags, hx, gxws);
    else
        lstm_fused<0><<<dim3(256), dim3(256), 0, stream>>>(
            x, h0, c0, Wf, Bf, Wi, Bi, Wc, Bc, Wo, Bo, out, flags, hx, gxws);
}

// Round 12
// 8026.530 us; speedup vs baseline: 1.9194x; 1.9194x over previous
//
#include <hip/hip_runtime.h>
#include <hip/hip_bf16.h>

// LSTM: L=1024, B=64, I=512, H=512, fp32 in/out.
// Persistent kernel, 256 WGs x 256 thr (1 WG/CU). 8 clusters x 32 WGs;
// cluster = 8 batches; wave = 16 gate rows (4 h-idx x 4 gates). Weights in
// VGPRs; C state in registers; x-GEMM in-loop (overlaps the wait = free,
// and paces the pollers — round-11 lesson).
// ROUND-12: WG-AGGREGATED EXCHANGE. Producer: active lanes -> 256B LDS tile
// -> syncthreads -> wave 0 stores 64 coalesced dwords (8x32B txns, was ~128
// scattered 2B) -> vmcnt(0) -> ONE per-WG flag (authoritative: drained).
// Consumer: poll 32 WG-flags -> 256-thread cooperative load of the cluster's
// 8KB h payload into XOR-swizzled LDS (32 WG-loads/cluster, was 128 wave-
// loads: 2MB -> 256KB per cluster-step) -> ds_read_b128 fragments.
// MALL txn count per step drops ~8x on loads and ~16x on stores; the MALL
// round-trip chain (store-drain -> flag -> poll -> load) stays, but without
// the congestion inflation.
// Reuse safety: flag(t-1) set => every wave of that WG passed its t-1
// publish-syncthreads => finished its lds_in reads of t-1 => staging writes
// for t can't race them; hx slots alternate by t&1.

typedef __attribute__((ext_vector_type(8))) short bf16x8;
typedef __attribute__((ext_vector_type(4))) float f32x4;

#define NT 1024
#define NB 64
#define NH 512
#define NI 512

#define FLAG_BYTES 4096
#define HX_OFF     4096    // u16[2][64][512] = 128 KiB

__device__ __forceinline__ bf16x8 pack8(float4 a, float4 b) {
    union U2 { __hip_bfloat162 h; unsigned int u; } c0, c1, c2, c3;
    c0.h = __float22bfloat162_rn(make_float2(a.x, a.y));
    c1.h = __float22bfloat162_rn(make_float2(a.z, a.w));
    c2.h = __float22bfloat162_rn(make_float2(b.x, b.y));
    c3.h = __float22bfloat162_rn(make_float2(b.z, b.w));
    union R { bf16x8 v; unsigned int u[4]; } r;
    r.u[0] = c0.u; r.u[1] = c1.u; r.u[2] = c2.u; r.u[3] = c3.u;
    return r.v;
}

__device__ __forceinline__ float sigm(float v) {
    return 1.0f / (1.0f + __expf(-v));
}
__device__ __forceinline__ float tanh_f(float v) {
    float e = __expf(-2.0f * fabsf(v));        // in (0,1], no overflow
    float r = (1.0f - e) / (1.0f + e);
    return copysignf(r, v);
}

__global__ __launch_bounds__(256, 1) void lstm_fused(
    const float* __restrict__ x,
    const float* __restrict__ h0,
    const float* __restrict__ c0,
    const float* __restrict__ Wf, const float* __restrict__ Bf,
    const float* __restrict__ Wi, const float* __restrict__ Bi,
    const float* __restrict__ Wc, const float* __restrict__ Bc,
    const float* __restrict__ Wo, const float* __restrict__ Bo,
    float* __restrict__ out,
    unsigned char* __restrict__ ws)
{
    unsigned int*   flags = (unsigned int*)ws;
    unsigned short* hx    = (unsigned short*)(ws + HX_OFF);

    // lds_in: 8 rows x 64 granules (16B) of h, granule-swizzled g^row.
    __shared__ unsigned long long lds_in[8 * 64 * 2];     // 8 KiB
    __shared__ unsigned short     h_out16[128];           // 256 B WG h tile

    const int tid  = threadIdx.x;
    const int wv   = tid >> 6;            // wave 0..3
    const int lane = tid & 63;
    const int n    = lane & 15;           // D col (gate row within wave tile)
    const int kg   = lane >> 4;           // k-group 0..3
    const int cl   = blockIdx.x & 7;      // cluster (XCD-swizzle heuristic)
    const int wg   = blockIdx.x >> 3;     // WG within cluster, 0..31

    const int jj = (wv << 2) + (n >> 2);          // 0..15 within WG
    const int j  = (wg << 4) + jj;                // global h index
    const int g  = n & 3;                         // 0=f 1=i 2=c 3=o

    const float* Wg = (g == 0) ? Wf : (g == 1) ? Wi : (g == 2) ? Wc : Wo;
    const float* Bg = (g == 0) ? Bf : (g == 1) ? Bi : (g == 2) ? Bc : Bo;

    const int m_a   = (n < 8) ? n : 7;            // A-row batch (8..15 dup)
    const int bglob = cl * 8 + m_a;

    // ---- prologue: static B-fragments (weights, bf16) into VGPRs ----
    bf16x8 bfrag[32];                             // [0..15]=h-part, [16..31]=x
    {
        const float* wrow = Wg + (size_t)j * (NH + NI);
        #pragma unroll
        for (int kb = 0; kb < 32; ++kb) {
            const float* p = wrow + kb * 32 + kg * 8;
            bfrag[kb] = pack8(*(const float4*)(p), *(const float4*)(p + 4));
        }
    }
    const float bias_v = Bg[j];

    const bool active = (g == 0) && (kg < 2);     // 8 lanes/wave x 4 regs
    float Cst[4];
    #pragma unroll
    for (int r = 0; r < 4; ++r)
        Cst[r] = active ? c0[(size_t)(cl * 8 + kg * 4 + r) * NH + j] : 0.0f;

    unsigned int* fb = flags + cl * 32;           // 32 per-WG flags, 128 B

    // cooperative-staging role of this thread
    const int srow = tid >> 5;                    // 0..7  (batch row in cluster)
    const int stt  = tid & 31;                    // 0..31 (granule pair)

    for (int t = 0; t < NT; ++t) {
        // -- x fragments + x-partial MFMAs (overlap producer lag; pacing) --
        const float* xrow = x + ((size_t)t * NB + bglob) * NI;
        bf16x8 xfrag[16];
        #pragma unroll
        for (int q = 0; q < 16; ++q) {
            const float* p = xrow + q * 32 + kg * 8;
            xfrag[q] = pack8(*(const float4*)(p), *(const float4*)(p + 4));
        }
        f32x4 a0 = {bias_v, bias_v, bias_v, bias_v};
        f32x4 a1 = {0.f, 0.f, 0.f, 0.f};
        f32x4 a2 = {0.f, 0.f, 0.f, 0.f};
        f32x4 a3 = {0.f, 0.f, 0.f, 0.f};
        #pragma unroll
        for (int q = 0; q < 16; q += 4) {
            a0 = __builtin_amdgcn_mfma_f32_16x16x32_bf16(xfrag[q],     bfrag[16 + q],     a0, 0, 0, 0);
            a1 = __builtin_amdgcn_mfma_f32_16x16x32_bf16(xfrag[q + 1], bfrag[16 + q + 1], a1, 0, 0, 0);
            a2 = __builtin_amdgcn_mfma_f32_16x16x32_bf16(xfrag[q + 2], bfrag[16 + q + 2], a2, 0, 0, 0);
            a3 = __builtin_amdgcn_mfma_f32_16x16x32_bf16(xfrag[q + 3], bfrag[16 + q + 3], a3, 0, 0, 0);
        }

        // -- wait: all 32 WG-flags of step t-1 (one u32 load, lanes 0..31) --
        if (t > 0) {
            const unsigned int tgt = (unsigned int)t;
            int guard = 1 << 20;
            for (;;) {
                bool ok = true;
                if (lane < 32) {
                    unsigned int fv = __hip_atomic_load(
                        fb + lane, __ATOMIC_RELAXED, __HIP_MEMORY_SCOPE_AGENT);
                    ok = (fv >= tgt);
                }
                if (__all(ok)) break;
                if (--guard == 0) break;          // hang safety
                __builtin_amdgcn_s_sleep(1);
            }
            __builtin_amdgcn_sched_barrier(0);    // keep h-loads after spin
        }

        // -- h fragments --
        bf16x8 hfrag[16];
        if (t == 0) {
            const float* hrow = h0 + (size_t)bglob * NH;
            #pragma unroll
            for (int q = 0; q < 16; ++q) {
                const float* p = hrow + q * 32 + kg * 8;
                hfrag[q] = pack8(*(const float4*)(p), *(const float4*)(p + 4));
            }
        } else {
            // cooperative 8KB load: thread (srow,stt) fetches granules
            // stt and stt+32 of batch row srow; LDS granule index g^row.
            const unsigned long long* src = (const unsigned long long*)hx
                + ((size_t)((t - 1) & 1) * NB + cl * 8 + srow) * (NH / 4);
            unsigned long long va = __hip_atomic_load(
                src + stt * 2,     __ATOMIC_RELAXED, __HIP_MEMORY_SCOPE_AGENT);
            unsigned long long vb = __hip_atomic_load(
                src + stt * 2 + 1, __ATOMIC_RELAXED, __HIP_MEMORY_SCOPE_AGENT);
            unsigned long long vc = __hip_atomic_load(
                src + 64 + stt * 2,     __ATOMIC_RELAXED, __HIP_MEMORY_SCOPE_AGENT);
            unsigned long long vd = __hip_atomic_load(
                src + 64 + stt * 2 + 1, __ATOMIC_RELAXED, __HIP_MEMORY_SCOPE_AGENT);
            const int g1 = stt ^ srow;
            const int g2 = (stt + 32) ^ srow;
            lds_in[(srow * 64 + g1) * 2]     = va;
            lds_in[(srow * 64 + g1) * 2 + 1] = vb;
            lds_in[(srow * 64 + g2) * 2]     = vc;
            lds_in[(srow * 64 + g2) * 2 + 1] = vd;
            __syncthreads();
            #pragma unroll
            for (int q = 0; q < 16; ++q) {
                const int gq = (q * 4 + kg) ^ m_a;
                hfrag[q] = *(const bf16x8*)&lds_in[(m_a * 64 + gq) * 2];
            }
        }

        #pragma unroll
        for (int q = 0; q < 16; q += 4) {
            a0 = __builtin_amdgcn_mfma_f32_16x16x32_bf16(hfrag[q],     bfrag[q],     a0, 0, 0, 0);
            a1 = __builtin_amdgcn_mfma_f32_16x16x32_bf16(hfrag[q + 1], bfrag[q + 1], a1, 0, 0, 0);
            a2 = __builtin_amdgcn_mfma_f32_16x16x32_bf16(hfrag[q + 2], bfrag[q + 2], a2, 0, 0, 0);
            a3 = __builtin_amdgcn_mfma_f32_16x16x32_bf16(hfrag[q + 3], bfrag[q + 3], a3, 0, 0, 0);
        }
        f32x4 acc = (a0 + a1) + (a2 + a3);

        // -- gather f/i/c/o in 4-lane groups, elementwise, h -> LDS tile --
        float harr[4];
        #pragma unroll
        for (int r = 0; r < 4; ++r) {
            float fv = acc[r];
            float iv = __shfl_xor(fv, 1);
            float gv = __shfl_xor(fv, 2);
            float ov = __shfl_xor(fv, 3);
            if (active) {
                float ft = sigm(fv);
                float it = sigm(iv);
                float gt = tanh_f(gv);
                float ot = sigm(ov);
                float Cn = ft * Cst[r] + it * gt;
                Cst[r] = Cn;
                float ht = ot * tanh_f(Cn);
                harr[r] = ht;
                __hip_bfloat16 hb = __float2bfloat16(ht);
                int m = kg * 4 + r;               // batch within cluster
                h_out16[m * 16 + jj] = *(unsigned short*)&hb;
            }
        }
        __syncthreads();                          // h_out16 complete (+ LDS)

        // -- wave 0: publish WG's 256B coalesced + drained flag --
        if (tid < 64) {
            unsigned int v = ((const unsigned int*)h_out16)[tid];
            const int m = tid >> 3;               // batch row 0..7
            const int c = tid & 7;                // dword within row tile
            unsigned int* dst = (unsigned int*)
                (hx + (size_t)(t & 1) * NB * NH
                    + (size_t)(cl * 8 + m) * NH + wg * 16) + c;
            __hip_atomic_store(dst, v, __ATOMIC_RELAXED,
                               __HIP_MEMORY_SCOPE_AGENT);
            asm volatile("s_waitcnt vmcnt(0)" ::: "memory");
            if (tid == 0)
                __hip_atomic_store(fb + wg, (unsigned int)(t + 1),
                                   __ATOMIC_RELAXED, __HIP_MEMORY_SCOPE_AGENT);
        }

        // -- fp32 output stores AFTER publish (off the critical path) --
        if (active) {
            #pragma unroll
            for (int r = 0; r < 4; ++r) {
                int m = kg * 4 + r;
                out[((size_t)t * NB + cl * 8 + m) * NH + j] = harr[r];
            }
        }
    }
}

extern "C" void kernel_launch(void* const* d_in, const int* in_sizes, int n_in,
                              void* d_out, int out_size, void* d_ws, size_t ws_size,
                              hipStream_t stream) {
    const float* x  = (const float*)d_in[0];
    const float* h0 = (const float*)d_in[1];
    const float* c0 = (const float*)d_in[2];
    const float* Wf = (const float*)d_in[3];
    const float* Bf = (const float*)d_in[4];
    const float* Wi = (const float*)d_in[5];
    const float* Bi = (const float*)d_in[6];
    const float* Wc = (const float*)d_in[7];
    const float* Bc = (const float*)d_in[8];
    const float* Wo = (const float*)d_in[9];
    const float* Bo = (const float*)d_in[10];
    float* out = (float*)d_out;

    // Flags: zero each launch (monotonic; authoritative gate for hx reads,
    // so hx itself needs no init and cross-replay staleness is impossible).
    hipMemsetAsync(d_ws, 0, FLAG_BYTES, stream);

    lstm_fused<<<dim3(256), dim3(256), 0, stream>>>(
        x, h0, c0, Wf, Bf, Wi, Bi, Wc, Bc, Wo, Bo, out,
        (unsigned char*)d_ws);
}

// Round 13
// 7793.869 us; speedup vs baseline: 1.9767x; 1.0299x over previous
//
#include <hip/hip_runtime.h>
#include <hip/hip_bf16.h>

// LSTM: L=1024, B=64, I=512, H=512, fp32 in/out.
// Persistent kernel, 256 WGs x 256 thr (1 WG/CU). 8 clusters x 32 WGs;
// cluster = 8 batches; wave = 16 gate rows (4 h-idx x 4 gates). Weights in
// VGPRs as MFMA B-fragments; C state in registers; x-GEMM in-loop (overlaps
// producer lag and paces the poll — round-11 lesson).
// ROUND-13: FLAGLESS, FUSED DETECT+LOAD. The h exchange is parity-coded
// (code = h_bits ^ (((t>>1)&1)?0xFFFF:0); |h|<=1 => bf16 bit14==0, coded
// parity-1 => bit14==1). Consumers poll the DATA: each iteration loads the
// full 8KB fragment set + validates bit14 across all words; the iteration
// that validates already has h in registers => detect RT and load RT are
// ONE round-trip (round 8 paid two). First iteration unpaced (hit = free);
// retries s_sleep(2)-paced (~0.1us) to bound fabric traffic (round-3/10
// failure mode). Producers: elementwise -> 4 coded 2B stores. No flags,
// no drains, no barriers anywhere in the steady-state path.
// Slot-reuse safety (no flags needed): producer stores h(t) only after
// validating ALL of h(t-1); every wave stored h(t-1) only after reading
// h(t-2) (program order) => slot t&1 == (t-2)&1 is no longer being read.
// Init/stale safety: hx memset 0x7F each launch (u16 0x7F7F: bit14=1,
// fails parity-0, which is what t=1/t=2 readers expect); within-launch
// stale data fails the alternating parity; cross-replay erased by memset.

typedef __attribute__((ext_vector_type(8))) short bf16x8;
typedef __attribute__((ext_vector_type(4))) float f32x4;

#define NT 1024
#define NB 64
#define NH 512
#define NI 512

#define HX_BYTES (2 * NB * NH * 2)    // 128 KiB double buffer

#define VBITS 0x4000400040004000ULL   // bit14 of each u16 lane

__device__ __forceinline__ bf16x8 pack8(float4 a, float4 b) {
    union U2 { __hip_bfloat162 h; unsigned int u; } c0, c1, c2, c3;
    c0.h = __float22bfloat162_rn(make_float2(a.x, a.y));
    c1.h = __float22bfloat162_rn(make_float2(a.z, a.w));
    c2.h = __float22bfloat162_rn(make_float2(b.x, b.y));
    c3.h = __float22bfloat162_rn(make_float2(b.z, b.w));
    union R { bf16x8 v; unsigned int u[4]; } r;
    r.u[0] = c0.u; r.u[1] = c1.u; r.u[2] = c2.u; r.u[3] = c3.u;
    return r.v;
}

__device__ __forceinline__ float sigm(float v) {
    return 1.0f / (1.0f + __expf(-v));
}
__device__ __forceinline__ float tanh_f(float v) {
    float e = __expf(-2.0f * fabsf(v));        // in (0,1], no overflow
    float r = (1.0f - e) / (1.0f + e);         // <= 1 in fp32
    return copysignf(r, v);
}

__global__ __launch_bounds__(256, 1) void lstm_fused(
    const float* __restrict__ x,
    const float* __restrict__ h0,
    const float* __restrict__ c0,
    const float* __restrict__ Wf, const float* __restrict__ Bf,
    const float* __restrict__ Wi, const float* __restrict__ Bi,
    const float* __restrict__ Wc, const float* __restrict__ Bc,
    const float* __restrict__ Wo, const float* __restrict__ Bo,
    float* __restrict__ out,
    unsigned short* __restrict__ hx)
{
    const int tid  = threadIdx.x;
    const int wv   = tid >> 6;            // wave 0..3
    const int lane = tid & 63;
    const int n    = lane & 15;           // D col (gate row within wave tile)
    const int kg   = lane >> 4;           // k-group 0..3
    const int cl   = blockIdx.x & 7;      // cluster (XCD-swizzle heuristic)
    const int wg   = blockIdx.x >> 3;     // WG within cluster, 0..31

    const int jj = (wv << 2) + (n >> 2);          // 0..15 within WG
    const int j  = (wg << 4) + jj;                // global h index
    const int g  = n & 3;                         // 0=f 1=i 2=c 3=o

    const float* Wg = (g == 0) ? Wf : (g == 1) ? Wi : (g == 2) ? Wc : Wo;
    const float* Bg = (g == 0) ? Bf : (g == 1) ? Bi : (g == 2) ? Bc : Bo;

    const int m_a   = (n < 8) ? n : 7;            // A-row batch (8..15 dup)
    const int bglob = cl * 8 + m_a;

    // ---- prologue: static B-fragments (weights, bf16) into VGPRs ----
    bf16x8 bfrag[32];                             // [0..15]=h-part, [16..31]=x
    {
        const float* wrow = Wg + (size_t)j * (NH + NI);
        #pragma unroll
        for (int kb = 0; kb < 32; ++kb) {
            const float* p = wrow + kb * 32 + kg * 8;
            bfrag[kb] = pack8(*(const float4*)(p), *(const float4*)(p + 4));
        }
    }
    const float bias_v = Bg[j];

    const bool active = (g == 0) && (kg < 2);     // 8 lanes/wave x 4 regs
    float Cst[4];
    #pragma unroll
    for (int r = 0; r < 4; ++r)
        Cst[r] = active ? c0[(size_t)(cl * 8 + kg * 4 + r) * NH + j] : 0.0f;

    for (int t = 0; t < NT; ++t) {
        // -- x fragments + x-partial MFMAs (overlap producer lag; pacing) --
        const float* xrow = x + ((size_t)t * NB + bglob) * NI;
        bf16x8 xfrag[16];
        #pragma unroll
        for (int q = 0; q < 16; ++q) {
            const float* p = xrow + q * 32 + kg * 8;
            xfrag[q] = pack8(*(const float4*)(p), *(const float4*)(p + 4));
        }
        f32x4 a0 = {bias_v, bias_v, bias_v, bias_v};
        f32x4 a1 = {0.f, 0.f, 0.f, 0.f};
        f32x4 a2 = {0.f, 0.f, 0.f, 0.f};
        f32x4 a3 = {0.f, 0.f, 0.f, 0.f};
        #pragma unroll
        for (int q = 0; q < 16; q += 4) {
            a0 = __builtin_amdgcn_mfma_f32_16x16x32_bf16(xfrag[q],     bfrag[16 + q],     a0, 0, 0, 0);
            a1 = __builtin_amdgcn_mfma_f32_16x16x32_bf16(xfrag[q + 1], bfrag[16 + q + 1], a1, 0, 0, 0);
            a2 = __builtin_amdgcn_mfma_f32_16x16x32_bf16(xfrag[q + 2], bfrag[16 + q + 2], a2, 0, 0, 0);
            a3 = __builtin_amdgcn_mfma_f32_16x16x32_bf16(xfrag[q + 3], bfrag[16 + q + 3], a3, 0, 0, 0);
        }

        // -- h fragments: FUSED poll+load (parity authoritative, no flags) --
        bf16x8 hfrag[16];
        if (t == 0) {
            const float* hrow = h0 + (size_t)bglob * NH;
            #pragma unroll
            for (int q = 0; q < 16; ++q) {
                const float* p = hrow + q * 32 + kg * 8;
                hfrag[q] = pack8(*(const float4*)(p), *(const float4*)(p + 4));
            }
        } else {
            const unsigned long long pm64 =
                (((t - 1) >> 1) & 1) ? ~0ULL : 0ULL;
            const unsigned short* hrow =
                hx + ((size_t)((t - 1) & 1) * NB + bglob) * NH;
            int attempt = 0;
            for (;;) {
                unsigned long long accb = 0;
                #pragma unroll
                for (int q = 0; q < 16; ++q) {
                    const unsigned long long* p =
                        (const unsigned long long*)(hrow + q * 32 + kg * 8);
                    union { bf16x8 v; unsigned long long u[2]; } un;
                    unsigned long long w0 = __hip_atomic_load(
                        p, __ATOMIC_RELAXED, __HIP_MEMORY_SCOPE_AGENT) ^ pm64;
                    unsigned long long w1 = __hip_atomic_load(
                        p + 1, __ATOMIC_RELAXED, __HIP_MEMORY_SCOPE_AGENT) ^ pm64;
                    accb |= w0;
                    accb |= w1;
                    un.u[0] = w0;
                    un.u[1] = w1;
                    hfrag[q] = un.v;
                }
                if (__all((accb & VBITS) == 0ULL)) break;   // valid => in regs
                if (++attempt > (1 << 14)) break;           // hang safety
                __builtin_amdgcn_s_sleep(2);                // paced retry
            }
            __builtin_amdgcn_sched_barrier(0);
        }

        #pragma unroll
        for (int q = 0; q < 16; q += 4) {
            a0 = __builtin_amdgcn_mfma_f32_16x16x32_bf16(hfrag[q],     bfrag[q],     a0, 0, 0, 0);
            a1 = __builtin_amdgcn_mfma_f32_16x16x32_bf16(hfrag[q + 1], bfrag[q + 1], a1, 0, 0, 0);
            a2 = __builtin_amdgcn_mfma_f32_16x16x32_bf16(hfrag[q + 2], bfrag[q + 2], a2, 0, 0, 0);
            a3 = __builtin_amdgcn_mfma_f32_16x16x32_bf16(hfrag[q + 3], bfrag[q + 3], a3, 0, 0, 0);
        }
        f32x4 acc = (a0 + a1) + (a2 + a3);

        // -- gather f/i/c/o in 4-lane groups, elementwise, coded h-store --
        unsigned short* hxout = hx + (size_t)(t & 1) * NB * NH;
        const unsigned int pmask = ((t >> 1) & 1) ? 0xFFFFu : 0u;
        float harr[4];
        #pragma unroll
        for (int r = 0; r < 4; ++r) {
            float fv = acc[r];
            float iv = __shfl_xor(fv, 1);
            float gv = __shfl_xor(fv, 2);
            float ov = __shfl_xor(fv, 3);
            if (active) {
                float ft = sigm(fv);
                float it = sigm(iv);
                float gt = tanh_f(gv);
                float ot = sigm(ov);
                float Cn = ft * Cst[r] + it * gt;
                Cst[r] = Cn;
                float ht = ot * tanh_f(Cn);       // |ht| <= 1.0 in fp32
                harr[r] = ht;
                int m = kg * 4 + r;               // batch within cluster
                __hip_bfloat16 hb = __float2bfloat16(ht);
                unsigned short code =
                    (unsigned short)((*(unsigned short*)&hb) ^ pmask);
                __hip_atomic_store(
                    (unsigned short*)(hxout + (size_t)(cl * 8 + m) * NH + j),
                    code, __ATOMIC_RELAXED, __HIP_MEMORY_SCOPE_AGENT);
            }
        }

        // -- fp32 output stores AFTER h publish (off the critical path) --
        if (active) {
            #pragma unroll
            for (int r = 0; r < 4; ++r) {
                int m = kg * 4 + r;
                out[((size_t)t * NB + cl * 8 + m) * NH + j] = harr[r];
            }
        }
    }
}

extern "C" void kernel_launch(void* const* d_in, const int* in_sizes, int n_in,
                              void* d_out, int out_size, void* d_ws, size_t ws_size,
                              hipStream_t stream) {
    const float* x  = (const float*)d_in[0];
    const float* h0 = (const float*)d_in[1];
    const float* c0 = (const float*)d_in[2];
    const float* Wf = (const float*)d_in[3];
    const float* Bf = (const float*)d_in[4];
    const float* Wi = (const float*)d_in[5];
    const float* Bi = (const float*)d_in[6];
    const float* Wc = (const float*)d_in[7];
    const float* Bc = (const float*)d_in[8];
    const float* Wo = (const float*)d_in[9];
    const float* Bo = (const float*)d_in[10];
    float* out = (float*)d_out;

    // hx: 0x7F each launch -> u16 0x7F7F has bit14==1: fails the parity-0
    // validator that t=1/t=2 readers use; erases all cross-replay data.
    // No flags to initialize — parity is the only gate.
    hipMemsetAsync(d_ws, 0x7F, HX_BYTES, stream);

    lstm_fused<<<dim3(256), dim3(256), 0, stream>>>(
        x, h0, c0, Wf, Bf, Wi, Bi, Wc, Bc, Wo, Bo, out,
        (unsigned short*)d_ws);
}